// Round 1
// baseline (27.722 us; speedup 1.0000x reference)
//
#include <hip/hip_runtime.h>

#define TILE 16
#define PPT 64

// Robustly read a small positive integer scalar that may have been stored
// as int32 or float32 bits.
__device__ __forceinline__ int read_dim(const int* p) {
    int v = *p;
    if (v >= TILE && v <= 65536 && (v % TILE) == 0) return v;
    float f = __int_as_float(v);
    return (int)f;
}

__global__ __launch_bounds__(256) void gsplat_raster_kernel(
    const float* __restrict__ point_uv,          // (N,2)
    const float* __restrict__ point_conic,       // (N,3)
    const float* __restrict__ point_alpha,       // (N,)
    const float* __restrict__ point_color,       // (N,3)
    const float* __restrict__ point_depth,       // (N,)
    const int*   __restrict__ tile_point_indices,// (NT,PPT)
    const int*   __restrict__ cam_h_p,
    const int*   __restrict__ cam_w_p,
    float* __restrict__ out)
{
    const int t = blockIdx.x;    // tile id
    const int p = threadIdx.x;   // pixel-in-tile id, 0..255

    const int W  = read_dim(cam_w_p);
    const int H  = read_dim(cam_h_p);
    const int TU = W / TILE;
    const int n_pix = H * W;

    // ---- stage this tile's 64 points into LDS (SoA) ----
    __shared__ float s_u[PPT], s_v[PPT];
    __shared__ float s_ca[PPT], s_cb[PPT], s_cc[PPT];
    __shared__ float s_al[PPT];
    __shared__ float s_r[PPT], s_g[PPT], s_b[PPT];
    __shared__ float s_d[PPT];

    if (p < PPT) {
        const int gi = tile_point_indices[t * PPT + p];
        s_u[p]  = point_uv[gi * 2 + 0];
        s_v[p]  = point_uv[gi * 2 + 1];
        s_ca[p] = point_conic[gi * 3 + 0];
        s_cb[p] = point_conic[gi * 3 + 1];
        s_cc[p] = point_conic[gi * 3 + 2];
        s_al[p] = point_alpha[gi];
        s_r[p]  = point_color[gi * 3 + 0];
        s_g[p]  = point_color[gi * 3 + 1];
        s_b[p]  = point_color[gi * 3 + 2];
        s_d[p]  = point_depth[gi];
    }
    __syncthreads();

    // ---- pixel coordinates ----
    const int tu = t % TU;
    const int tv = t / TU;
    const int pu = p % TILE;   // pixel col within tile
    const int pv = p / TILE;   // pixel row within tile
    const float pix_u = (float)(tu * TILE + pu) + 0.5f;
    const float pix_v = (float)(tv * TILE + pv) + 0.5f;

    // ---- sequential front-to-back compositing ----
    float T = 1.0f;
    float accr = 0.0f, accg = 0.0f, accb = 0.0f;
    float accd = 0.0f, norm = 0.0f;
    int count = 0, last = 0;

    #pragma unroll 4
    for (int j = 0; j < PPT; ++j) {
        const float dx = pix_u - s_u[j];
        const float dy = pix_v - s_v[j];
        const float power = -0.5f * (s_ca[j] * dx * dx + s_cc[j] * dy * dy)
                            - s_cb[j] * dx * dy;
        const float alpha = expf(power) * s_al[j];

        // visible = alpha >= 1/255; invisible points have one_m == 1 and
        // affect nothing -> skip exactly.
        if (!(alpha >= (1.0f / 255.0f))) continue;

        const float alpha_c = fminf(alpha, 0.99f);
        const float one_m   = 1.0f - alpha_c;

        // trigger = visible & (Ti * one_m < 1e-4). cumsum(trigger) > 0 makes
        // the triggering point itself non-contributing, and everything after.
        if (T * one_m < 1e-4f) break;

        const float w = alpha_c * T;
        accr += w * s_r[j];
        accg += w * s_g[j];
        accb += w * s_b[j];
        accd += w * s_d[j];
        norm += w;
        count += 1;
        last = j + 1;
        T *= one_m;
    }

    // ---- write outputs (image layout) ----
    const int r = tv * TILE + pv;
    const int c = tu * TILE + pu;
    const int pix = r * W + c;

    // out0: rasterized_image (H,W,3)
    out[pix * 3 + 0] = accr;
    out[pix * 3 + 1] = accg;
    out[pix * 3 + 2] = accb;
    // out1: rasterized_depth (H,W)
    out[n_pix * 3 + pix] = accd / fmaxf(norm, 1e-6f);
    // out2: pixel_accumulated_alpha (H,W)
    out[n_pix * 4 + pix] = 1.0f - T;
    // out3: pixel_offset_of_last_effective_point (H,W) — int stored as float
    out[n_pix * 5 + pix] = (float)(t * PPT + last);
    // out4: pixel_valid_point_count (H,W) — int stored as float
    out[n_pix * 6 + pix] = (float)count;
}

extern "C" void kernel_launch(void* const* d_in, const int* in_sizes, int n_in,
                              void* d_out, int out_size, void* d_ws, size_t ws_size,
                              hipStream_t stream) {
    const float* point_uv    = (const float*)d_in[0];
    const float* point_conic = (const float*)d_in[1];
    const float* point_alpha = (const float*)d_in[2];
    const float* point_color = (const float*)d_in[3];
    const float* point_depth = (const float*)d_in[4];
    const int*   tpi         = (const int*)d_in[5];
    const int*   cam_h       = (const int*)d_in[6];
    const int*   cam_w       = (const int*)d_in[7];

    const int NT = in_sizes[5] / PPT;  // 1024 tiles

    gsplat_raster_kernel<<<NT, 256, 0, stream>>>(
        point_uv, point_conic, point_alpha, point_color, point_depth,
        tpi, cam_h, cam_w, (float*)d_out);
}

// Round 2
// 27.165 us; speedup vs baseline: 1.0205x; 1.0205x over previous
//
#include <hip/hip_runtime.h>
#include <cmath>

#define TILE 16
#define PPT 64

// Robustly read a small positive integer scalar that may have been stored
// as int32 or float32 bits.
__device__ __forceinline__ int read_dim(const int* p) {
    int v = *p;
    if (v >= TILE && v <= 65536 && (v % TILE) == 0) return v;
    float f = __int_as_float(v);
    return (int)f;
}

__global__ __launch_bounds__(256) void gsplat_raster_kernel(
    const float* __restrict__ point_uv,          // (N,2)
    const float* __restrict__ point_conic,       // (N,3)
    const float* __restrict__ point_alpha,       // (N,)
    const float* __restrict__ point_color,       // (N,3)
    const float* __restrict__ point_depth,       // (N,)
    const int*   __restrict__ tile_point_indices,// (NT,PPT)
    const int*   __restrict__ cam_h_p,
    const int*   __restrict__ cam_w_p,
    float* __restrict__ out)
{
    const int t = blockIdx.x;    // tile id
    const int p = threadIdx.x;   // pixel-in-tile id, 0..255

    const int W  = read_dim(cam_w_p);
    const int H  = read_dim(cam_h_p);
    const int TU = W / TILE;
    const int n_pix = H * W;

    // ---- stage this tile's 64 points into LDS, packed for b128 reads ----
    // sA = {u, v, -0.5a, -0.5c}   (conic pre-scaled by EXACT factors)
    // sB = {-b, alpha, col_r, col_g}
    // sC = {col_b, depth}
    __shared__ float4 sA[PPT];
    __shared__ float4 sB[PPT];
    __shared__ float2 sC[PPT];

    if (p < PPT) {
        const int gi = tile_point_indices[t * PPT + p];
        const float u  = point_uv[gi * 2 + 0];
        const float v  = point_uv[gi * 2 + 1];
        const float ca = point_conic[gi * 3 + 0];
        const float cb = point_conic[gi * 3 + 1];
        const float cc = point_conic[gi * 3 + 2];
        sA[p] = make_float4(u, v, -0.5f * ca, -0.5f * cc);
        sB[p] = make_float4(-cb, point_alpha[gi],
                            point_color[gi * 3 + 0], point_color[gi * 3 + 1]);
        sC[p] = make_float2(point_color[gi * 3 + 2], point_depth[gi]);
    }
    __syncthreads();

    // ---- pixel coordinates ----
    const int tu = t % TU;
    const int tv = t / TU;
    const int pu = p % TILE;   // pixel col within tile
    const int pv = p / TILE;   // pixel row within tile
    const float pix_u = (float)(tu * TILE + pu) + 0.5f;
    const float pix_v = (float)(tv * TILE + pv) + 0.5f;

    // ---- sequential front-to-back compositing ----
    float T = 1.0f;
    float accr = 0.0f, accg = 0.0f, accb = 0.0f;
    float accd = 0.0f, norm = 0.0f;
    int count = 0, last = 0;

    const float INV255 = 1.0f / 255.0f;
    const float GUARD  = INV255 * 1e-3f;   // visibility-boundary guard band

    #pragma unroll 4
    for (int j = 0; j < PPT; ++j) {
        const float4 A = sA[j];   // u, v, pa, pc   (wave-uniform broadcast)
        const float4 B = sB[j];   // pb, al, r, g
        const float2 C = sC[j];   // b, d

        const float dx = pix_u - A.x;
        const float dy = pix_v - A.y;
        // power = -0.5*(a dx^2 + c dy^2) - b dx dy, via exact pre-scaled coeffs
        const float power = fmaf(A.z, dx * dx,
                            fmaf(A.w, dy * dy, B.x * (dx * dy)));

        // fast exp: v_exp_f32 (exp2) with single log2e multiply
        float alpha = __expf(power) * B.y;

        // Guard: if fast alpha sits near the visibility boundary, recompute
        // with the precise expf so the visible/invisible decision matches
        // the reference. Taken ~never per wave (s_cbranch_execz skips).
        if (fabsf(alpha - INV255) < GUARD) {
            alpha = expf(power) * B.y;
        }

        // invisible points have one_m == 1 and affect nothing -> skip exactly
        if (!(alpha >= INV255)) continue;

        const float alpha_c = fminf(alpha, 0.99f);
        const float one_m   = 1.0f - alpha_c;

        // trigger = visible & (Ti * one_m < 1e-4): triggering point itself
        // does not contribute, nor does anything after it.
        if (T * one_m < 1e-4f) break;

        const float w = alpha_c * T;
        accr = fmaf(w, B.z, accr);
        accg = fmaf(w, B.w, accg);
        accb = fmaf(w, C.x, accb);
        accd = fmaf(w, C.y, accd);
        norm += w;
        count += 1;
        last = j + 1;
        T *= one_m;
    }

    // ---- write outputs (image layout) ----
    const int r = tv * TILE + pv;
    const int c = tu * TILE + pu;
    const int pix = r * W + c;

    // out0: rasterized_image (H,W,3)
    out[pix * 3 + 0] = accr;
    out[pix * 3 + 1] = accg;
    out[pix * 3 + 2] = accb;
    // out1: rasterized_depth (H,W)
    out[n_pix * 3 + pix] = accd / fmaxf(norm, 1e-6f);
    // out2: pixel_accumulated_alpha (H,W)
    out[n_pix * 4 + pix] = 1.0f - T;
    // out3: pixel_offset_of_last_effective_point (H,W) — int stored as float
    out[n_pix * 5 + pix] = (float)(t * PPT + last);
    // out4: pixel_valid_point_count (H,W) — int stored as float
    out[n_pix * 6 + pix] = (float)count;
}

extern "C" void kernel_launch(void* const* d_in, const int* in_sizes, int n_in,
                              void* d_out, int out_size, void* d_ws, size_t ws_size,
                              hipStream_t stream) {
    const float* point_uv    = (const float*)d_in[0];
    const float* point_conic = (const float*)d_in[1];
    const float* point_alpha = (const float*)d_in[2];
    const float* point_color = (const float*)d_in[3];
    const float* point_depth = (const float*)d_in[4];
    const int*   tpi         = (const int*)d_in[5];
    const int*   cam_h       = (const int*)d_in[6];
    const int*   cam_w       = (const int*)d_in[7];

    const int NT = in_sizes[5] / PPT;  // number of tiles

    gsplat_raster_kernel<<<NT, 256, 0, stream>>>(
        point_uv, point_conic, point_alpha, point_depth ? point_color : point_color,
        point_depth, tpi, cam_h, cam_w, (float*)d_out);
}

// Round 3
// 20.307 us; speedup vs baseline: 1.3651x; 1.3377x over previous
//
#include <hip/hip_runtime.h>
#include <hip/hip_fp16.h>

#define TILE 16
#define PPT 64

#if __has_builtin(__builtin_amdgcn_exp2f)
#define EXP2F(x) __builtin_amdgcn_exp2f(x)
#else
#define EXP2F(x) exp2f(x)
#endif

// Robustly read a small positive integer scalar that may have been stored
// as int32 or float32 bits.
__device__ __forceinline__ int read_dim(const int* p) {
    int v = *p;
    if (v >= TILE && v <= 65536 && (v % TILE) == 0) return v;
    float f = __int_as_float(v);
    return (int)f;
}

__global__ __launch_bounds__(256, 4) void gsplat_raster_kernel(
    const float* __restrict__ point_uv,          // (N,2)
    const float* __restrict__ point_conic,       // (N,3)
    const float* __restrict__ point_alpha,       // (N,)
    const float* __restrict__ point_color,       // (N,3)
    const float* __restrict__ point_depth,       // (N,)
    const int*   __restrict__ tile_point_indices,// (NT,PPT)
    const int*   __restrict__ cam_h_p,
    const int*   __restrict__ cam_w_p,
    float* __restrict__ out)
{
    const int t = blockIdx.x;    // tile id
    const int p = threadIdx.x;   // pixel-in-tile id, 0..255

    const int W  = read_dim(cam_w_p);
    const int H  = read_dim(cam_h_p);
    const int TU = W / TILE;
    const int n_pix = H * W;

    // ---- stage 64 points into LDS: exactly 2 broadcast b128 reads/iter ----
    // sA = {u, v, -0.5*a*log2e, -0.5*c*log2e}
    // sB = {-b*log2e, log2(alpha), half2(r,g), half2(b,depth)}
    __shared__ float4 sA[PPT];
    __shared__ float4 sB[PPT];

    const float L2E = 1.4426950408889634f;
    if (p < PPT) {                       // wave 0: A-side
        const int gi = tile_point_indices[t * PPT + p];
        const float2 uv = ((const float2*)point_uv)[gi];
        const float ca = point_conic[gi * 3 + 0];
        const float cc = point_conic[gi * 3 + 2];
        sA[p] = make_float4(uv.x, uv.y, -0.5f * L2E * ca, -0.5f * L2E * cc);
    } else if (p < 2 * PPT) {            // wave 1: B-side
        const int q  = p - PPT;
        const int gi = tile_point_indices[t * PPT + q];
        const float cb = point_conic[gi * 3 + 1];
        const float al = point_alpha[gi];
        const __half2 rg = __floats2half2_rn(point_color[gi * 3 + 0],
                                             point_color[gi * 3 + 1]);
        const __half2 bd = __floats2half2_rn(point_color[gi * 3 + 2],
                                             point_depth[gi]);
        sB[q] = make_float4(-L2E * cb, __log2f(al),
                            __builtin_bit_cast(float, rg),
                            __builtin_bit_cast(float, bd));
    }
    __syncthreads();

    // ---- pixel coordinates ----
    const int tu = t % TU;
    const int tv = t / TU;
    const int pu = p % TILE;
    const int pv = p / TILE;
    const float pix_u = (float)(tu * TILE + pu) + 0.5f;
    const float pix_v = (float)(tv * TILE + pv) + 0.5f;

    // ---- branchless front-to-back compositing ----
    float T = 1.0f;
    float accr = 0.0f, accg = 0.0f, accb = 0.0f;
    float accd = 0.0f, norm = 0.0f;
    int count = 0, last = 0;
    bool sat = false;

    for (int c8 = 0; c8 < PPT / 8; ++c8) {
        #pragma unroll
        for (int k = 0; k < 8; ++k) {
            const int j = c8 * 8 + k;
            const float4 A = sA[j];   // wave-uniform broadcast
            const float4 B = sB[j];

            const float dx = pix_u - A.x;
            const float dy = pix_v - A.y;
            // e = log2(dens * alpha) = pa*dx^2 + pb*dx*dy + pc*dy^2 + lal
            const float e = fmaf(fmaf(A.z, dx, B.x * dy), dx,
                                 fmaf(A.w * dy, dy, B.y));
            const float alpha = EXP2F(e);

            const bool  vis     = alpha >= (1.0f / 255.0f);
            const float alpha_c = fminf(alpha, 0.99f);
            const float one_m   = 1.0f - alpha_c;
            const float Tone    = T * one_m;
            const bool  ntrig   = Tone >= 1e-4f;
            const bool  contrib = vis && ntrig && !sat;
            sat = sat || (vis && !ntrig);

            const float w = contrib ? alpha_c * T : 0.0f;
            const __half2 rg = __builtin_bit_cast(__half2, B.z);
            const __half2 bd = __builtin_bit_cast(__half2, B.w);
            accr = fmaf(w, __low2float(rg),  accr);
            accg = fmaf(w, __high2float(rg), accg);
            accb = fmaf(w, __low2float(bd),  accb);
            accd = fmaf(w, __high2float(bd), accd);
            norm += w;
            count += contrib;
            last = contrib ? j + 1 : last;
            T = contrib ? Tone : T;
        }
        if (__all(sat)) break;   // whole wave saturated: remaining w == 0
    }

    // ---- write outputs (image layout) ----
    const int r = tv * TILE + pv;
    const int c = tu * TILE + pu;
    const int pix = r * W + c;

    out[pix * 3 + 0] = accr;                       // rasterized_image
    out[pix * 3 + 1] = accg;
    out[pix * 3 + 2] = accb;
    out[n_pix * 3 + pix] = accd / fmaxf(norm, 1e-6f);   // rasterized_depth
    out[n_pix * 4 + pix] = 1.0f - T;                    // accumulated_alpha
    out[n_pix * 5 + pix] = (float)(t * PPT + last);     // last_offset (int as float)
    out[n_pix * 6 + pix] = (float)count;                // valid_count  (int as float)
}

extern "C" void kernel_launch(void* const* d_in, const int* in_sizes, int n_in,
                              void* d_out, int out_size, void* d_ws, size_t ws_size,
                              hipStream_t stream) {
    const float* point_uv    = (const float*)d_in[0];
    const float* point_conic = (const float*)d_in[1];
    const float* point_alpha = (const float*)d_in[2];
    const float* point_color = (const float*)d_in[3];
    const float* point_depth = (const float*)d_in[4];
    const int*   tpi         = (const int*)d_in[5];
    const int*   cam_h       = (const int*)d_in[6];
    const int*   cam_w       = (const int*)d_in[7];

    const int NT = in_sizes[5] / PPT;  // number of tiles

    gsplat_raster_kernel<<<NT, 256, 0, stream>>>(
        point_uv, point_conic, point_alpha, point_color, point_depth,
        tpi, cam_h, cam_w, (float*)d_out);
}